// Round 5
// baseline (5105.196 us; speedup 1.0000x reference)
//
#include <hip/hip_runtime.h>

// Pool_FPS: furthest point sampling (B=8, N=32768, K=1024) + gather (C=128).
// FPS kernel: 1 block per batch, 1024 threads, 32 pts/thread, blocks-of-4.
//
// ROUND 0-4 LESSON: allocator pins this kernel at 64 arch VGPRs regardless of
// __launch_bounds__ / amdgpu_waves_per_eu; any resident set >~64 floats goes
// to scratch (L2-backed, FETCH_SIZE-invisible) and costs ~3.3us/iter.
// THIS ROUND: design INTO 64 VGPRs. Only ds[32] (read-modify-write) lives in
// registers. x,y are RE-READ from global each iteration (input is 1.5MB,
// L2-resident; ~256KB/iter/CU hides under the 3072cy VALU stream). z in LDS.
// Blocks-of-4 ownership: n = g*4096 + tid*4 + e -> global_load_dwordx4 for
// x,y and ds_read_b128 for z; in-thread n ascending so strict-> tie-break
// still yields the exact numpy first-occurrence argmax.
//
//  - exact fp32: d = ((dx*dx + dy*dy) + dz*dz), rn ops, no fma contraction.
//  - one barrier per iter: wave argmax -> 16 LDS slots (parity-buffered) ->
//    barrier -> every wave: 1 LDS read (16 lanes) + 4 shfl_xor -> uniform.
//  - centers via readfirstlane + scalar (SGPR) L2-resident loads.
// Gather kernel: one thread per output element.

#define BATCH 8
#define NPTS 32768
#define KSEL 1024
#define CFEAT 128
#define TPB 1024
#define GROUPS 8                 // 8 groups * 4 pts = 32 pts/thread
#define NWAVE (TPB / 64)         // 16 waves

__global__ void
__attribute__((amdgpu_flat_work_group_size(TPB, TPB), amdgpu_waves_per_eu(1, 4)))
fps_kernel(const float* __restrict__ xyz, int* __restrict__ idxbuf) {
    extern __shared__ float smem[];
    float* zsh = smem;                       // [NPTS] 128KB
    float* sd  = smem + NPTS;                // [2][NWAVE] parity-buffered wave maxima
    int*   sn  = (int*)(smem + NPTS + 2 * NWAVE);  // [2][NWAVE]

    const int b   = blockIdx.x;
    const int tid = threadIdx.x;
    const float* Xp = xyz + (size_t)b * 3 * NPTS;
    const float* Yp = Xp + NPTS;
    const float* Zp = Xp + 2 * NPTS;
    const float4* X4 = (const float4*)Xp;
    const float4* Y4 = (const float4*)Yp;
    const float4* Z4 = (const float4*)Zp;
    float4* ZS4 = (float4*)zsh;

    float ds[GROUPS][4];
#pragma unroll
    for (int g = 0; g < GROUPS; ++g) {
        ZS4[g * TPB + tid] = Z4[g * TPB + tid];   // stage z into LDS (b128)
#pragma unroll
        for (int e = 0; e < 4; ++e) ds[g][e] = __builtin_inff();
    }
    if (tid == 0) idxbuf[(size_t)b * KSEL] = 0;   // idx[0] = 0
    float cx = Xp[0], cy = Yp[0], cz = Zp[0];
    __syncthreads();

    const int lane = tid & 63;
    const int wid  = tid >> 6;

    for (int t = 1; t < KSEL; ++t) {
        float bd = -__builtin_inff();
        int   bj = 0;
#pragma unroll
        for (int g = 0; g < GROUPS; ++g) {
            const float4 x4 = X4[g * TPB + tid];   // L2-resident re-read
            const float4 y4 = Y4[g * TPB + tid];
            const float4 z4 = ZS4[g * TPB + tid];  // ds_read_b128
            const float* xe = (const float*)&x4;
            const float* ye = (const float*)&y4;
            const float* ze = (const float*)&z4;
#pragma unroll
            for (int e = 0; e < 4; ++e) {
                const float dx = xe[e] - cx;
                const float dy = ye[e] - cy;
                const float dz = ze[e] - cz;
                // exact: ((dx*dx + dy*dy) + dz*dz), rn, no fma contraction
                const float d = __fadd_rn(__fadd_rn(__fmul_rn(dx, dx), __fmul_rn(dy, dy)),
                                          __fmul_rn(dz, dz));
                const float nd = fminf(ds[g][e], d);
                ds[g][e] = nd;
                // strict > keeps smallest (g,e) => smallest n for this thread
                const bool gt = nd > bd;
                bd = gt ? nd : bd;
                bj = gt ? (g * 4 + e) : bj;
            }
        }
        int bn = (bj >> 2) * (TPB * 4) + tid * 4 + (bj & 3);
        // wave argmax: max d, tie -> min index
#pragma unroll
        for (int off = 32; off >= 1; off >>= 1) {
            const float od = __shfl_xor(bd, off);
            const int   on = __shfl_xor(bn, off);
            if (od > bd || (od == bd && on < bn)) { bd = od; bn = on; }
        }
        const int p = (t & 1) * NWAVE;
        if (lane == 0) { sd[p + wid] = bd; sn[p + wid] = bn; }
        __syncthreads();
        // every wave reduces the 16 slots: 1 LDS read (16 active lanes) + 4 shfl
        float rd = (lane < NWAVE) ? sd[p + lane] : -__builtin_inff();
        int   rn = (lane < NWAVE) ? sn[p + lane] : 0x7FFFFFFF;
#pragma unroll
        for (int off = 8; off >= 1; off >>= 1) {
            const float od = __shfl_xor(rd, off);
            const int   on = __shfl_xor(rn, off);
            if (od > rd || (od == rd && on < rn)) { rd = od; rn = on; }
        }
        const int rns = __builtin_amdgcn_readfirstlane(rn);
        if (tid == 0) idxbuf[(size_t)b * KSEL + t] = rns;
        // scalar (SGPR) center fetch, L2-resident
        cx = Xp[rns]; cy = Yp[rns]; cz = Zp[rns];
    }
}

__global__ void gather_kernel(const float* __restrict__ xyz,
                              const float* __restrict__ feat,
                              const int* __restrict__ idxbuf,
                              float* __restrict__ out) {
    const int SN = BATCH * 3 * KSEL;                  // 24576
    const int total = SN + BATCH * CFEAT * KSEL;      // 1073152
    const int i = blockIdx.x * blockDim.x + threadIdx.x;
    if (i >= total) return;
    if (i < SN) {
        const int b = i / (3 * KSEL);
        const int r = i - b * 3 * KSEL;
        const int c = r / KSEL;
        const int k = r - c * KSEL;
        const int n = idxbuf[b * KSEL + k];
        out[i] = xyz[((size_t)b * 3 + c) * NPTS + n];
    } else {
        const int i2 = i - SN;
        const int b = i2 / (CFEAT * KSEL);
        const int r = i2 - b * CFEAT * KSEL;
        const int c = r / KSEL;
        const int k = r - c * KSEL;
        const int n = idxbuf[b * KSEL + k];
        out[SN + i2] = feat[((size_t)b * CFEAT + c) * NPTS + n];
    }
}

extern "C" void kernel_launch(void* const* d_in, const int* in_sizes, int n_in,
                              void* d_out, int out_size, void* d_ws, size_t ws_size,
                              hipStream_t stream) {
    const float* xyz  = (const float*)d_in[0];
    const float* feat = (const float*)d_in[1];
    float* out = (float*)d_out;
    int* idxbuf = (int*)d_ws;  // BATCH*KSEL ints = 32KB

    const size_t smem_bytes = (size_t)(NPTS + 4 * NWAVE) * sizeof(float);  // ~128.25KB
    hipFuncSetAttribute((const void*)fps_kernel,
                        hipFuncAttributeMaxDynamicSharedMemorySize, (int)smem_bytes);

    fps_kernel<<<BATCH, TPB, smem_bytes, stream>>>(xyz, idxbuf);

    const int total = BATCH * 3 * KSEL + BATCH * CFEAT * KSEL;  // 1073152
    gather_kernel<<<(total + 255) / 256, 256, 0, stream>>>(xyz, feat, idxbuf, out);
}

// Round 6
// 3653.202 us; speedup vs baseline: 1.3975x; 1.3975x over previous
//
#include <hip/hip_runtime.h>

// Pool_FPS: furthest point sampling (B=8, N=32768, K=1024) + gather (C=128).
//
// ROUND 0-5 LESSONS: single-block-per-batch is structurally stuck at ~4.7ms:
// 3×128KB of coords can't fit LDS, allocator won't exceed 64 VGPRs, so x/y
// traffic (scratch OR explicit re-read) exposes ~200cy L2 latency 6-8x/iter.
// THIS ROUND: 8 worker blocks per batch (grid=64, cooperative launch). Each
// block owns 4096 pts -> x,y,z + ds all in REGISTERS (16 VGPRs/thread);
// 48KB static LDS holds a coord copy only for winner lookup. Per iteration:
// block-local argmax (wave bfly + 16 LDS slots), then wave0 publishes
// (d,n,x,y,z) to a global slot (agent-scope atomics), release-adds a per-batch
// counter, acquire-spins to 8t, reads 8 slots, bfly-reduces (max d, tie ->
// min index = exact numpy argmax), broadcasts center via LDS. No slot reset
// needed: one writer per slot per iter; counter release-sequence orders all.
// Counters zeroed each launch via hipMemsetAsync (graph/replay-safe).
// Correctness does NOT depend on XCD placement; cooperative launch guarantees
// co-residency (64 blocks <= 256 CUs).
//  - exact fp32: d = ((dx*dx + dy*dy) + dz*dz), rn ops, no fma contraction.

#define BATCH 8
#define NPTS 32768
#define KSEL 1024
#define CFEAT 128
#define WPB 8                    // worker blocks per batch
#define LOCN (NPTS / WPB)        // 4096 points per block
#define TPB 1024                 // 4 points per thread
#define NWAVE (TPB / 64)         // 16 waves

#define AT_ST(p, v) __hip_atomic_store((p), (v), __ATOMIC_RELAXED, __HIP_MEMORY_SCOPE_AGENT)
#define AT_LD(p)    __hip_atomic_load((p), __ATOMIC_RELAXED, __HIP_MEMORY_SCOPE_AGENT)

__global__ void
__attribute__((amdgpu_flat_work_group_size(TPB, TPB)))
fps_kernel(const float* __restrict__ xyz, char* __restrict__ ws) {
    int* idxbuf     = (int*)ws;                       // [BATCH*KSEL]
    unsigned* cnts  = (unsigned*)(ws + 32768);        // stride 16 u32 per batch
    char* sb        = ws + 32768 + 512;
    float* sd_g     = (float*)(sb);                   // [64] partial max d
    int*   sn_g     = (int*)(sb + 256);               // [64] partial argmax (batch-global)
    float* sx_g     = (float*)(sb + 512);
    float* sy_g     = (float*)(sb + 768);
    float* sz_g     = (float*)(sb + 1024);

    __shared__ float4 lx4[TPB], ly4[TPB], lz4[TPB];   // 48KB: winner coord lookup
    __shared__ float swd[NWAVE];
    __shared__ int   swn[NWAVE];
    __shared__ float scen[3];

    const int bid = blockIdx.x;
    const int b   = bid & 7;          // batch
    const int blk = bid >> 3;         // worker id within batch
    const int tid = threadIdx.x;
    const int lane = tid & 63;
    const int wid  = tid >> 6;

    const float* Xp = xyz + (size_t)b * 3 * NPTS;
    const float* Yp = Xp + NPTS;
    const float* Zp = Xp + 2 * NPTS;

    // own 4 consecutive points: global idx gn0 = blk*4096 + tid*4
    const int o4 = blk * (LOCN / 4) + tid;            // float4 index into batch arrays
    const float4 x4 = ((const float4*)Xp)[o4];
    const float4 y4 = ((const float4*)Yp)[o4];
    const float4 z4 = ((const float4*)Zp)[o4];
    lx4[tid] = x4; ly4[tid] = y4; lz4[tid] = z4;
    float ds0 = __builtin_inff(), ds1 = __builtin_inff(),
          ds2 = __builtin_inff(), ds3 = __builtin_inff();

    if (blk == 0 && tid == 0) idxbuf[(size_t)b * KSEL] = 0;   // idx[0] = 0
    float cx = Xp[0], cy = Yp[0], cz = Zp[0];
    __syncthreads();

    const float* xe = (const float*)&x4;
    const float* ye = (const float*)&y4;
    const float* ze = (const float*)&z4;

    for (int t = 1; t < KSEL; ++t) {
        // ---- update ds, thread-local argmax (4 pts, all in regs) ----
        float bd = -__builtin_inff();
        int   be = 0;
        float* dsp[4] = {&ds0, &ds1, &ds2, &ds3};
#pragma unroll
        for (int e = 0; e < 4; ++e) {
            const float dx = xe[e] - cx;
            const float dy = ye[e] - cy;
            const float dz = ze[e] - cz;
            // exact: ((dx*dx + dy*dy) + dz*dz), rn, no fma contraction
            const float d = __fadd_rn(__fadd_rn(__fmul_rn(dx, dx), __fmul_rn(dy, dy)),
                                      __fmul_rn(dz, dz));
            const float nd = fminf(*dsp[e], d);
            *dsp[e] = nd;
            const bool gt = nd > bd;      // strict > keeps smallest e
            bd = gt ? nd : bd;
            be = gt ? e : be;
        }
        int bn = tid * 4 + be;            // block-local point index
        // ---- wave argmax (max d, tie -> min index) ----
#pragma unroll
        for (int off = 32; off >= 1; off >>= 1) {
            const float od = __shfl_xor(bd, off);
            const int   on = __shfl_xor(bn, off);
            if (od > bd || (od == bd && on < bn)) { bd = od; bn = on; }
        }
        if (lane == 0) { swd[wid] = bd; swn[wid] = bn; }
        __syncthreads();

        if (wid == 0) {
            // ---- block reduce over 16 wave slots (dup-safe: lane&15) ----
            float rd = swd[lane & 15];
            int   rn = swn[lane & 15];
#pragma unroll
            for (int off = 8; off >= 1; off >>= 1) {
                const float od = __shfl_xor(rd, off);
                const int   on = __shfl_xor(rn, off);
                if (od > rd || (od == rd && on < rn)) { rd = od; rn = on; }
            }
            // winner coords from LDS (uniform addr broadcast)
            const float wx = ((const float*)lx4)[rn];
            const float wy = ((const float*)ly4)[rn];
            const float wz = ((const float*)lz4)[rn];
            const int   gn = blk * LOCN + rn;         // batch-global index
            const int   sl0 = b * WPB + blk;
            if (lane == 0) {
                AT_ST(&sd_g[sl0], rd); AT_ST(&sn_g[sl0], gn);
                AT_ST(&sx_g[sl0], wx); AT_ST(&sy_g[sl0], wy); AT_ST(&sz_g[sl0], wz);
                __hip_atomic_fetch_add(&cnts[b * 16], 1u, __ATOMIC_RELEASE,
                                       __HIP_MEMORY_SCOPE_AGENT);
            }
            // ---- spin until all 8 workers of this batch arrived ----
            while (__hip_atomic_load(&cnts[b * 16], __ATOMIC_ACQUIRE,
                                     __HIP_MEMORY_SCOPE_AGENT) < (unsigned)(WPB * t)) {}
            // ---- reduce the 8 partials (dup-safe: lane&7) ----
            const int sl = b * WPB + (lane & 7);
            float od = AT_LD(&sd_g[sl]);
            int   on = AT_LD(&sn_g[sl]);
            float ox = AT_LD(&sx_g[sl]);
            float oy = AT_LD(&sy_g[sl]);
            float oz = AT_LD(&sz_g[sl]);
#pragma unroll
            for (int off = 4; off >= 1; off >>= 1) {
                const float pd = __shfl_xor(od, off);
                const int   pn = __shfl_xor(on, off);
                const float px = __shfl_xor(ox, off);
                const float py = __shfl_xor(oy, off);
                const float pz = __shfl_xor(oz, off);
                if (pd > od || (pd == od && pn < on)) {
                    od = pd; on = pn; ox = px; oy = py; oz = pz;
                }
            }
            if (lane == 0) {
                scen[0] = ox; scen[1] = oy; scen[2] = oz;
                if (blk == 0) idxbuf[(size_t)b * KSEL + t] = on;
            }
        }
        __syncthreads();
        cx = scen[0]; cy = scen[1]; cz = scen[2];
    }
}

__global__ void gather_kernel(const float* __restrict__ xyz,
                              const float* __restrict__ feat,
                              const int* __restrict__ idxbuf,
                              float* __restrict__ out) {
    const int SN = BATCH * 3 * KSEL;                  // 24576
    const int total = SN + BATCH * CFEAT * KSEL;      // 1073152
    const int i = blockIdx.x * blockDim.x + threadIdx.x;
    if (i >= total) return;
    if (i < SN) {
        const int b = i / (3 * KSEL);
        const int r = i - b * 3 * KSEL;
        const int c = r / KSEL;
        const int k = r - c * KSEL;
        const int n = idxbuf[b * KSEL + k];
        out[i] = xyz[((size_t)b * 3 + c) * NPTS + n];
    } else {
        const int i2 = i - SN;
        const int b = i2 / (CFEAT * KSEL);
        const int r = i2 - b * CFEAT * KSEL;
        const int c = r / KSEL;
        const int k = r - c * KSEL;
        const int n = idxbuf[b * KSEL + k];
        out[SN + i2] = feat[((size_t)b * CFEAT + c) * NPTS + n];
    }
}

extern "C" void kernel_launch(void* const* d_in, const int* in_sizes, int n_in,
                              void* d_out, int out_size, void* d_ws, size_t ws_size,
                              hipStream_t stream) {
    const float* xyz  = (const float*)d_in[0];
    const float* feat = (const float*)d_in[1];
    float* out = (float*)d_out;
    char* ws = (char*)d_ws;
    // ws layout: [0,32KB) idxbuf | [32KB,32.5KB) counters | [32.5KB, +1.25KB) slots

    // zero the per-batch arrival counters every call (replay-safe)
    hipMemsetAsync(ws + 32768, 0, 512, stream);

    void* args[] = {(void*)&xyz, (void*)&ws};
    hipLaunchCooperativeKernel((const void*)fps_kernel,
                               dim3(BATCH * WPB), dim3(TPB), args, 0, stream);

    int* idxbuf = (int*)d_ws;
    const int total = BATCH * 3 * KSEL + BATCH * CFEAT * KSEL;  // 1073152
    gather_kernel<<<(total + 255) / 256, 256, 0, stream>>>(xyz, feat, idxbuf, out);
}

// Round 7
// 3383.539 us; speedup vs baseline: 1.5088x; 1.0797x over previous
//
#include <hip/hip_runtime.h>

// Pool_FPS: furthest point sampling (B=8, N=32768, K=1024) + gather (C=128).
//
// ROUND-6 LESSON: acquire/release agent-scope atomics flush/invalidate the
// XCD L2 EVERY iteration (FETCH 1.8->5.8MB, WRITE 0.4->12.5MB) -> ~3.2us/iter
// of sync. THIS ROUND: fence-free protocol. Each of 8 worker blocks packs its
// partial argmax into ONE u64  [d:32 | t:10 | n:15]  and publishes with a
// RELAXED agent atomic store to a parity slot; all waves spin on RELAXED
// atomic loads until all 8 slots carry tag t (tag = freshness, no ordering
// needed). Winner coords are re-fetched by scalar loads from L2 (read-only
// data, no race). No counter, no fences, no L2 flushes, one barrier/iter.
//
// Exactness: d = ((dx*dx+dy*dy)+dz*dz), rn ops, no fma contraction; argmax
// tie-break = smallest global index at every reduce level (strict > on d,
// then min n). idx[0]=0. Matches numpy/jax bit-exactly (R1-R6 all absmax=0).
//
// Replay-safe: slots zeroed via hipMemsetAsync each launch (tag 0 never
// matches t>=1); idxbuf fully rewritten every call.

#define BATCH 8
#define NPTS 32768
#define KSEL 1024
#define CFEAT 128
#define WPB 8                    // worker blocks per batch
#define LOCN (NPTS / WPB)        // 4096 points per block
#define TPB 1024                 // 4 points per thread
#define NWAVE (TPB / 64)         // 16 waves

typedef unsigned long long u64;

#define AT_ST(p, v) __hip_atomic_store((p), (v), __ATOMIC_RELAXED, __HIP_MEMORY_SCOPE_AGENT)
#define AT_LD(p)    __hip_atomic_load((p), __ATOMIC_RELAXED, __HIP_MEMORY_SCOPE_AGENT)

__global__ void
__attribute__((amdgpu_flat_work_group_size(TPB, TPB)))
fps_kernel(const float* __restrict__ xyz, char* __restrict__ ws) {
    int* idxbuf = (int*)ws;                     // [BATCH*KSEL]
    u64* slots  = (u64*)(ws + 32768);           // [2][BATCH][WPB] parity slot sets

    __shared__ float swd[NWAVE];
    __shared__ int   swn[NWAVE];

    const int bid  = blockIdx.x;
    const int b    = bid & 7;                   // batch
    const int blk  = bid >> 3;                  // worker id within batch
    const int tid  = threadIdx.x;
    const int lane = tid & 63;
    const int wid  = tid >> 6;

    const float* Xp = xyz + (size_t)b * 3 * NPTS;
    const float* Yp = Xp + NPTS;
    const float* Zp = Xp + 2 * NPTS;

    // own 4 consecutive points: global idx = blk*LOCN + tid*4 + e
    const int o4 = blk * (LOCN / 4) + tid;
    const float4 x4 = ((const float4*)Xp)[o4];
    const float4 y4 = ((const float4*)Yp)[o4];
    const float4 z4 = ((const float4*)Zp)[o4];
    const float* xe = (const float*)&x4;
    const float* ye = (const float*)&y4;
    const float* ze = (const float*)&z4;
    float ds[4] = {__builtin_inff(), __builtin_inff(),
                   __builtin_inff(), __builtin_inff()};

    if (blk == 0 && tid == 0) idxbuf[(size_t)b * KSEL] = 0;   // idx[0] = 0
    float cx = Xp[0], cy = Yp[0], cz = Zp[0];

    for (int t = 1; t < KSEL; ++t) {
        // ---- update ds, thread-local argmax (4 pts, all in regs) ----
        float bd = -__builtin_inff();
        int   be = 0;
#pragma unroll
        for (int e = 0; e < 4; ++e) {
            const float dx = xe[e] - cx;
            const float dy = ye[e] - cy;
            const float dz = ze[e] - cz;
            // exact: ((dx*dx + dy*dy) + dz*dz), rn, no fma contraction
            const float d = __fadd_rn(__fadd_rn(__fmul_rn(dx, dx), __fmul_rn(dy, dy)),
                                      __fmul_rn(dz, dz));
            const float nd = fminf(ds[e], d);
            ds[e] = nd;
            const bool gt = nd > bd;        // strict > keeps smallest e
            bd = gt ? nd : bd;
            be = gt ? e : be;
        }
        int bn = tid * 4 + be;              // block-local point index
        // ---- wave argmax (max d, tie -> min index) ----
#pragma unroll
        for (int off = 32; off >= 1; off >>= 1) {
            const float od = __shfl_xor(bd, off);
            const int   on = __shfl_xor(bn, off);
            if (od > bd || (od == bd && on < bn)) { bd = od; bn = on; }
        }
        if (lane == 0) { swd[wid] = bd; swn[wid] = bn; }
        __syncthreads();   // also orders: swd reads(t-1) << publish(t-1) << poll-exit(t-1) << these writes

        if (wid == 0) {
            // ---- block reduce over 16 wave slots (dup-safe: lane&15) ----
            float rd = swd[lane & 15];
            int   rn = swn[lane & 15];
#pragma unroll
            for (int off = 8; off >= 1; off >>= 1) {
                const float od = __shfl_xor(rd, off);
                const int   on = __shfl_xor(rn, off);
                if (od > rd || (od == rd && on < rn)) { rd = od; rn = on; }
            }
            if (lane == 0) {
                const int gn = blk * LOCN + rn;          // batch-global index
                const u64 v = ((u64)__float_as_uint(rd) << 32)
                            | ((u64)(t & 1023) << 15) | (u64)gn;
                AT_ST(&slots[(size_t)(t & 1) * (BATCH * WPB) + b * WPB + blk], v);
            }
        }

        // ---- every wave polls the 8 slots (relaxed; tag==t => fresh) ----
        u64* sp = &slots[(size_t)(t & 1) * (BATCH * WPB) + b * WPB];
        u64 v;
        do {
            v = AT_LD(&sp[lane & 7]);
        } while (!__all((int)((v >> 15) & 1023) == t));
        // ---- reduce the 8 partials (pattern period 8 -> bfly 4,2,1) ----
        float od = __uint_as_float((unsigned)(v >> 32));
        int   on = (int)(v & 32767);
#pragma unroll
        for (int off = 4; off >= 1; off >>= 1) {
            const float pd = __shfl_xor(od, off);
            const int   pn = __shfl_xor(on, off);
            if (pd > od || (pd == od && pn < on)) { od = pd; on = pn; }
        }
        const int gw = __builtin_amdgcn_readfirstlane(on);
        if (blk == 0 && tid == 0) idxbuf[(size_t)b * KSEL + t] = gw;
        // scalar (SGPR) center fetch from XCD-local L2 (read-only data)
        cx = Xp[gw]; cy = Yp[gw]; cz = Zp[gw];
    }
}

__global__ void gather_kernel(const float* __restrict__ xyz,
                              const float* __restrict__ feat,
                              const int* __restrict__ idxbuf,
                              float* __restrict__ out) {
    const int SN = BATCH * 3 * KSEL;                  // 24576
    const int total = SN + BATCH * CFEAT * KSEL;      // 1073152
    const int i = blockIdx.x * blockDim.x + threadIdx.x;
    if (i >= total) return;
    if (i < SN) {
        const int b = i / (3 * KSEL);
        const int r = i - b * 3 * KSEL;
        const int c = r / KSEL;
        const int k = r - c * KSEL;
        const int n = idxbuf[b * KSEL + k];
        out[i] = xyz[((size_t)b * 3 + c) * NPTS + n];
    } else {
        const int i2 = i - SN;
        const int b = i2 / (CFEAT * KSEL);
        const int r = i2 - b * CFEAT * KSEL;
        const int c = r / KSEL;
        const int k = r - c * KSEL;
        const int n = idxbuf[b * KSEL + k];
        out[SN + i2] = feat[((size_t)b * CFEAT + c) * NPTS + n];
    }
}

extern "C" void kernel_launch(void* const* d_in, const int* in_sizes, int n_in,
                              void* d_out, int out_size, void* d_ws, size_t ws_size,
                              hipStream_t stream) {
    const float* xyz  = (const float*)d_in[0];
    const float* feat = (const float*)d_in[1];
    float* out = (float*)d_out;
    char* ws = (char*)d_ws;
    // ws layout: [0,32KB) idxbuf | [32KB, +1KB) u64 slots [2][8][8]

    // zero the slot tags every call (tag 0 never matches t>=1) — replay-safe
    hipMemsetAsync(ws + 32768, 0, 2 * BATCH * WPB * sizeof(u64), stream);

    void* args[] = {(void*)&xyz, (void*)&ws};
    hipLaunchCooperativeKernel((const void*)fps_kernel,
                               dim3(BATCH * WPB), dim3(TPB), args, 0, stream);

    int* idxbuf = (int*)d_ws;
    const int total = BATCH * 3 * KSEL + BATCH * CFEAT * KSEL;  // 1073152
    gather_kernel<<<(total + 255) / 256, 256, 0, stream>>>(xyz, feat, idxbuf, out);
}

// Round 9
// 2529.337 us; speedup vs baseline: 2.0184x; 1.3377x over previous
//
#include <hip/hip_runtime.h>

// Pool_FPS: furthest point sampling (B=8, N=32768, K=1024) + gather (C=128).
//
// ROUND-8 LESSON: the sc0 "XCD-L2-scope" fast path DEADLOCKED (600s timeout)
// - sc0-only load/store on gfx950 is NOT glc-like L1-bypass; the poll spun on
// a cache level the remote store never reached. Rule: never gate a spin-loop
// exit on unverified cache-scope semantics. REVERTED to the R7 agent-scope
// relaxed-atomic protocol (bit-exact, proven) and kept only the safe half of
// R8: wave0-only polling + 2nd barrier + LDS winner broadcast (poll
// contention /16 vs R7, where 16 waves x 8 blocks hammered the IF point).
//
// Protocol (unchanged from R7): each of 8 worker blocks packs its partial
// argmax into ONE u64 [d:32 | tag:10 | n:15], relaxed-agent-stores it to a
// parity slot; wave0 polls the 8 slots with relaxed loads until all carry
// tag t (tag = freshness; single-word atomicity => no fences needed; parity
// + tag chain => single-writer race-free). Winner coords re-fetched as
// scalar loads of read-only L2-cached data.
//
// Exactness: d = ((dx*dx+dy*dy)+dz*dz), rn ops, no fma contraction; argmax
// tie-break = smallest global index at every reduce level. idx[0]=0.
// Replay-safe: slots zeroed via hipMemsetAsync each launch.

#define BATCH 8
#define NPTS 32768
#define KSEL 1024
#define CFEAT 128
#define WPB 8                    // worker blocks per batch
#define LOCN (NPTS / WPB)        // 4096 points per block
#define TPB 1024                 // 4 points per thread
#define NWAVE (TPB / 64)         // 16 waves

typedef unsigned long long u64;

#define AT_ST(p, v) __hip_atomic_store((p), (v), __ATOMIC_RELAXED, __HIP_MEMORY_SCOPE_AGENT)
#define AT_LD(p)    __hip_atomic_load((p), __ATOMIC_RELAXED, __HIP_MEMORY_SCOPE_AGENT)

__global__ void
__attribute__((amdgpu_flat_work_group_size(TPB, TPB)))
fps_kernel(const float* __restrict__ xyz, char* __restrict__ ws) {
    int* idxbuf = (int*)ws;                     // [BATCH*KSEL] 32KB
    u64* slots  = (u64*)(ws + 32768);           // [2][BATCH][WPB] parity slot sets

    __shared__ float swd[NWAVE];
    __shared__ int   swn[NWAVE];
    __shared__ int   sgw;

    const int bid  = blockIdx.x;
    const int b    = bid & 7;                   // batch
    const int blk  = bid >> 3;                  // worker id within batch
    const int tid  = threadIdx.x;
    const int lane = tid & 63;
    const int wid  = tid >> 6;

    const float* Xp = xyz + (size_t)b * 3 * NPTS;
    const float* Yp = Xp + NPTS;
    const float* Zp = Xp + 2 * NPTS;

    // own 4 consecutive points: global idx = blk*LOCN + tid*4 + e
    const int o4 = blk * (LOCN / 4) + tid;
    const float4 x4 = ((const float4*)Xp)[o4];
    const float4 y4 = ((const float4*)Yp)[o4];
    const float4 z4 = ((const float4*)Zp)[o4];
    const float* xe = (const float*)&x4;
    const float* ye = (const float*)&y4;
    const float* ze = (const float*)&z4;
    float ds[4] = {__builtin_inff(), __builtin_inff(),
                   __builtin_inff(), __builtin_inff()};

    if (blk == 0 && tid == 0) idxbuf[(size_t)b * KSEL] = 0;   // idx[0] = 0
    float cx = Xp[0], cy = Yp[0], cz = Zp[0];

    for (int t = 1; t < KSEL; ++t) {
        // ---- update ds, thread-local argmax (4 pts, all in regs) ----
        float bd = -__builtin_inff();
        int   be = 0;
#pragma unroll
        for (int e = 0; e < 4; ++e) {
            const float dx = xe[e] - cx;
            const float dy = ye[e] - cy;
            const float dz = ze[e] - cz;
            // exact: ((dx*dx + dy*dy) + dz*dz), rn, no fma contraction
            const float d = __fadd_rn(__fadd_rn(__fmul_rn(dx, dx), __fmul_rn(dy, dy)),
                                      __fmul_rn(dz, dz));
            const float nd = fminf(ds[e], d);
            ds[e] = nd;
            const bool gt = nd > bd;        // strict > keeps smallest e
            bd = gt ? nd : bd;
            be = gt ? e : be;
        }
        int bn = tid * 4 + be;              // block-local point index
        // ---- wave argmax (max d, tie -> min index) ----
#pragma unroll
        for (int off = 32; off >= 1; off >>= 1) {
            const float od = __shfl_xor(bd, off);
            const int   on = __shfl_xor(bn, off);
            if (od > bd || (od == bd && on < bn)) { bd = od; bn = on; }
        }
        if (lane == 0) { swd[wid] = bd; swn[wid] = bn; }
        __syncthreads();                    // barrier #1

        if (wid == 0) {
            // ---- block reduce over 16 wave slots (dup-safe: lane&15) ----
            float rd = swd[lane & 15];
            int   rn = swn[lane & 15];
#pragma unroll
            for (int off = 8; off >= 1; off >>= 1) {
                const float od = __shfl_xor(rd, off);
                const int   on = __shfl_xor(rn, off);
                if (od > rd || (od == rd && on < rn)) { rd = od; rn = on; }
            }
            u64* slotbase = &slots[(size_t)(t & 1) * (BATCH * WPB) + b * WPB];
            if (lane == 0) {
                const int gn = blk * LOCN + rn;          // batch-global index
                const u64 v = ((u64)__float_as_uint(rd) << 32)
                            | ((u64)(t & 1023) << 15) | (u64)gn;
                AT_ST(&slotbase[blk], v);
            }
            // ---- wave0-only poll of the 8 slots (tag==t => fresh) ----
            u64 v;
            do { v = AT_LD(&slotbase[lane & 7]); }
            while (!__all((int)((v >> 15) & 1023) == t));
            // ---- reduce the 8 partials (period 8 -> bfly 4,2,1) ----
            float od = __uint_as_float((unsigned)(v >> 32));
            int   on = (int)(v & 32767);
#pragma unroll
            for (int off = 4; off >= 1; off >>= 1) {
                const float pd = __shfl_xor(od, off);
                const int   pn = __shfl_xor(on, off);
                if (pd > od || (pd == od && pn < on)) { od = pd; on = pn; }
            }
            if (lane == 0) sgw = on;
        }
        __syncthreads();                    // barrier #2
        const int gw = sgw;
        if (blk == 0 && tid == 0) idxbuf[(size_t)b * KSEL + t] = gw;
        // scalar (SGPR) center fetch of read-only data (L1/L2 cached)
        cx = Xp[gw]; cy = Yp[gw]; cz = Zp[gw];
    }
}

__global__ void gather_kernel(const float* __restrict__ xyz,
                              const float* __restrict__ feat,
                              const int* __restrict__ idxbuf,
                              float* __restrict__ out) {
    const int SN = BATCH * 3 * KSEL;                  // 24576
    const int total = SN + BATCH * CFEAT * KSEL;      // 1073152
    const int i = blockIdx.x * blockDim.x + threadIdx.x;
    if (i >= total) return;
    if (i < SN) {
        const int b = i / (3 * KSEL);
        const int r = i - b * 3 * KSEL;
        const int c = r / KSEL;
        const int k = r - c * KSEL;
        const int n = idxbuf[b * KSEL + k];
        out[i] = xyz[((size_t)b * 3 + c) * NPTS + n];
    } else {
        const int i2 = i - SN;
        const int b = i2 / (CFEAT * KSEL);
        const int r = i2 - b * CFEAT * KSEL;
        const int c = r / KSEL;
        const int k = r - c * KSEL;
        const int n = idxbuf[b * KSEL + k];
        out[SN + i2] = feat[((size_t)b * CFEAT + c) * NPTS + n];
    }
}

extern "C" void kernel_launch(void* const* d_in, const int* in_sizes, int n_in,
                              void* d_out, int out_size, void* d_ws, size_t ws_size,
                              hipStream_t stream) {
    const float* xyz  = (const float*)d_in[0];
    const float* feat = (const float*)d_in[1];
    float* out = (float*)d_out;
    char* ws = (char*)d_ws;
    // ws layout: [0,32KB) idxbuf | [32KB, +1KB) u64 slots [2][8][8]

    // zero the slot tags every call (tag 0 never matches t>=1) — replay-safe
    hipMemsetAsync(ws + 32768, 0, 2 * BATCH * WPB * sizeof(u64), stream);

    void* args[] = {(void*)&xyz, (void*)&ws};
    hipLaunchCooperativeKernel((const void*)fps_kernel,
                               dim3(BATCH * WPB), dim3(TPB), args, 0, stream);

    int* idxbuf = (int*)d_ws;
    const int total = BATCH * 3 * KSEL + BATCH * CFEAT * KSEL;  // 1073152
    gather_kernel<<<(total + 255) / 256, 256, 0, stream>>>(xyz, feat, idxbuf, out);
}

// Round 10
// 2406.285 us; speedup vs baseline: 2.1216x; 1.0511x over previous
//
#include <hip/hip_runtime.h>

// Pool_FPS: furthest point sampling (B=8, N=32768, K=1024) + gather (C=128).
//
// ROUND-9 STATE: 8 worker blocks/batch + relaxed agent-scope u64 slot
// protocol, wave0-only poll = 2.50ms (2.44us/iter vs 0.35us compute).
// Residual = IF-point sync latency: store-visible (~0.35us) + poll DETECT
// GRANULARITY (~800cy single load in flight -> up to 2 periods lag) + local
// reduce tail. THIS ROUND:
//  (a) 4-deep pipelined poll: 4 independent relaxed loads in flight, check
//      oldest first -> detect lag ~800cy -> ~200-300cy. Each 8B word is
//      individually atomic + tag-verified, so any-hit-exit is order-safe.
//  (b) TPB 1024->512 (8 pts/thread): halves barrier population, shortens
//      block reduce (8 slots, 3 bfly levels). VGPR ~40 < 64-reg ceiling.
// Protocol otherwise unchanged from R9 (bit-exact, proven): u64 slot
// [d:32|tag:10|n:15], parity-indexed; tag==t proves freshness; no fences.
//
// Exactness: d = ((dx*dx+dy*dy)+dz*dz), rn ops, no fma contraction; argmax
// tie-break = smallest global index at every reduce level. idx[0]=0.
// Replay-safe: slots zeroed via hipMemsetAsync each launch.

#define BATCH 8
#define NPTS 32768
#define KSEL 1024
#define CFEAT 128
#define WPB 8                    // worker blocks per batch
#define LOCN (NPTS / WPB)        // 4096 points per block
#define TPB 512                  // 8 points per thread
#define PPT 8
#define NWAVE (TPB / 64)         // 8 waves

typedef unsigned long long u64;

#define AT_ST(p, v) __hip_atomic_store((p), (v), __ATOMIC_RELAXED, __HIP_MEMORY_SCOPE_AGENT)
#define AT_LD(p)    __hip_atomic_load((p), __ATOMIC_RELAXED, __HIP_MEMORY_SCOPE_AGENT)
#define TAG(v)      ((int)(((v) >> 15) & 1023))

__global__ void
__attribute__((amdgpu_flat_work_group_size(TPB, TPB)))
fps_kernel(const float* __restrict__ xyz, char* __restrict__ ws) {
    int* idxbuf = (int*)ws;                     // [BATCH*KSEL] 32KB
    u64* slots  = (u64*)(ws + 32768);           // [2][BATCH][WPB] parity slot sets

    __shared__ float swd[NWAVE];
    __shared__ int   swn[NWAVE];
    __shared__ int   sgw;

    const int bid  = blockIdx.x;
    const int b    = bid & 7;                   // batch
    const int blk  = bid >> 3;                  // worker id within batch
    const int tid  = threadIdx.x;
    const int lane = tid & 63;
    const int wid  = tid >> 6;

    const float* Xp = xyz + (size_t)b * 3 * NPTS;
    const float* Yp = Xp + NPTS;
    const float* Zp = Xp + 2 * NPTS;
    const float4* X4 = (const float4*)Xp;
    const float4* Y4 = (const float4*)Yp;
    const float4* Z4 = (const float4*)Zp;

    // own 8 consecutive points: global idx = blk*LOCN + tid*8 + e
    const int f4 = blk * (LOCN / 4) + 2 * tid;
    const float4 xa = X4[f4], xb = X4[f4 + 1];
    const float4 ya = Y4[f4], yb = Y4[f4 + 1];
    const float4 za = Z4[f4], zb = Z4[f4 + 1];
    float xs[PPT] = {xa.x, xa.y, xa.z, xa.w, xb.x, xb.y, xb.z, xb.w};
    float ys[PPT] = {ya.x, ya.y, ya.z, ya.w, yb.x, yb.y, yb.z, yb.w};
    float zs[PPT] = {za.x, za.y, za.z, za.w, zb.x, zb.y, zb.z, zb.w};
    float ds[PPT];
#pragma unroll
    for (int e = 0; e < PPT; ++e) ds[e] = __builtin_inff();

    if (blk == 0 && tid == 0) idxbuf[(size_t)b * KSEL] = 0;   // idx[0] = 0
    float cx = Xp[0], cy = Yp[0], cz = Zp[0];

    for (int t = 1; t < KSEL; ++t) {
        // ---- update ds, thread-local argmax (8 pts, all in regs) ----
        float bd = -__builtin_inff();
        int   be = 0;
#pragma unroll
        for (int e = 0; e < PPT; ++e) {
            const float dx = xs[e] - cx;
            const float dy = ys[e] - cy;
            const float dz = zs[e] - cz;
            // exact: ((dx*dx + dy*dy) + dz*dz), rn, no fma contraction
            const float d = __fadd_rn(__fadd_rn(__fmul_rn(dx, dx), __fmul_rn(dy, dy)),
                                      __fmul_rn(dz, dz));
            const float nd = fminf(ds[e], d);
            ds[e] = nd;
            const bool gt = nd > bd;        // strict > keeps smallest e
            bd = gt ? nd : bd;
            be = gt ? e : be;
        }
        int bn = tid * PPT + be;            // block-local point index (0..4095)
        // ---- wave argmax (max d, tie -> min index) ----
#pragma unroll
        for (int off = 32; off >= 1; off >>= 1) {
            const float od = __shfl_xor(bd, off);
            const int   on = __shfl_xor(bn, off);
            if (od > bd || (od == bd && on < bn)) { bd = od; bn = on; }
        }
        if (lane == 0) { swd[wid] = bd; swn[wid] = bn; }
        __syncthreads();                    // barrier #1

        if (wid == 0) {
            // ---- block reduce over 8 wave slots (dup-safe: lane&7) ----
            float rd = swd[lane & 7];
            int   rn = swn[lane & 7];
#pragma unroll
            for (int off = 4; off >= 1; off >>= 1) {
                const float od = __shfl_xor(rd, off);
                const int   on = __shfl_xor(rn, off);
                if (od > rd || (od == rd && on < rn)) { rd = od; rn = on; }
            }
            u64* slotbase = &slots[(size_t)(t & 1) * (BATCH * WPB) + b * WPB];
            if (lane == 0) {
                const int gn = blk * LOCN + rn;          // batch-global index
                const u64 v = ((u64)__float_as_uint(rd) << 32)
                            | ((u64)(t & 1023) << 15) | (u64)gn;
                AT_ST(&slotbase[blk], v);
            }
            // ---- 4-deep pipelined poll (tag==t => fresh; any-hit exit) ----
            u64* sp = &slotbase[lane & 7];
            u64 v;
            for (;;) {
                const u64 v0 = AT_LD(sp);
                const u64 v1 = AT_LD(sp);
                const u64 v2 = AT_LD(sp);
                const u64 v3 = AT_LD(sp);
                if (__all(TAG(v0) == t)) { v = v0; break; }
                if (__all(TAG(v1) == t)) { v = v1; break; }
                if (__all(TAG(v2) == t)) { v = v2; break; }
                if (__all(TAG(v3) == t)) { v = v3; break; }
            }
            // ---- reduce the 8 partials (period 8 -> bfly 4,2,1) ----
            float od = __uint_as_float((unsigned)(v >> 32));
            int   on = (int)(v & 32767);
#pragma unroll
            for (int off = 4; off >= 1; off >>= 1) {
                const float pd = __shfl_xor(od, off);
                const int   pn = __shfl_xor(on, off);
                if (pd > od || (pd == od && pn < on)) { od = pd; on = pn; }
            }
            if (lane == 0) sgw = on;
        }
        __syncthreads();                    // barrier #2
        const int gw = sgw;
        if (blk == 0 && tid == 0) idxbuf[(size_t)b * KSEL + t] = gw;
        // scalar (SGPR) center fetch of read-only data (L1/L2 cached)
        cx = Xp[gw]; cy = Yp[gw]; cz = Zp[gw];
    }
}

__global__ void gather_kernel(const float* __restrict__ xyz,
                              const float* __restrict__ feat,
                              const int* __restrict__ idxbuf,
                              float* __restrict__ out) {
    const int SN = BATCH * 3 * KSEL;                  // 24576
    const int total = SN + BATCH * CFEAT * KSEL;      // 1073152
    const int i = blockIdx.x * blockDim.x + threadIdx.x;
    if (i >= total) return;
    if (i < SN) {
        const int b = i / (3 * KSEL);
        const int r = i - b * 3 * KSEL;
        const int c = r / KSEL;
        const int k = r - c * KSEL;
        const int n = idxbuf[b * KSEL + k];
        out[i] = xyz[((size_t)b * 3 + c) * NPTS + n];
    } else {
        const int i2 = i - SN;
        const int b = i2 / (CFEAT * KSEL);
        const int r = i2 - b * CFEAT * KSEL;
        const int c = r / KSEL;
        const int k = r - c * KSEL;
        const int n = idxbuf[b * KSEL + k];
        out[SN + i2] = feat[((size_t)b * CFEAT + c) * NPTS + n];
    }
}

extern "C" void kernel_launch(void* const* d_in, const int* in_sizes, int n_in,
                              void* d_out, int out_size, void* d_ws, size_t ws_size,
                              hipStream_t stream) {
    const float* xyz  = (const float*)d_in[0];
    const float* feat = (const float*)d_in[1];
    float* out = (float*)d_out;
    char* ws = (char*)d_ws;
    // ws layout: [0,32KB) idxbuf | [32KB, +1KB) u64 slots [2][8][8]

    // zero the slot tags every call (tag 0 never matches t>=1) — replay-safe
    hipMemsetAsync(ws + 32768, 0, 2 * BATCH * WPB * sizeof(u64), stream);

    void* args[] = {(void*)&xyz, (void*)&ws};
    hipLaunchCooperativeKernel((const void*)fps_kernel,
                               dim3(BATCH * WPB), dim3(TPB), args, 0, stream);

    int* idxbuf = (int*)d_ws;
    const int total = BATCH * 3 * KSEL + BATCH * CFEAT * KSEL;  // 1073152
    gather_kernel<<<(total + 255) / 256, 256, 0, stream>>>(xyz, feat, idxbuf, out);
}